// Round 10
// baseline (1304.380 us; speedup 1.0000x reference)
//
#include <hip/hip_runtime.h>
#include <hip/hip_bf16.h>

#define EMB_D 100
#define HID 64
#define G4 256
#define BATCH 128
#define SEQ 1024
#define TOK 16

typedef _Float16 half2v __attribute__((ext_vector_type(2)));
typedef unsigned short u16;
typedef unsigned int   u32;

__device__ __forceinline__ float sigf(float x) { return 1.0f / (1.0f + __expf(-x)); }
__device__ __forceinline__ float tanh_fast(float x) {
  float t = __expf(-2.0f * fabsf(x));
  float r = (1.0f - t) / (1.0f + t);
  return copysignf(r, x);
}
__device__ __forceinline__ float dot2(u32 h, u32 w, float acc) {
  return __builtin_amdgcn_fdot2(__builtin_bit_cast(half2v, h),
                                __builtin_bit_cast(half2v, w), acc, false);
}
__device__ __forceinline__ u32 packh2(float lo, float hi) {
  u16 a = __builtin_bit_cast(u16, (_Float16)lo);
  u16 b = __builtin_bit_cast(u16, (_Float16)hi);
  return (u32)a | ((u32)b << 16);
}
// sum over each 8-lane group: quad xor1, quad xor2, row half-mirror.
// dpp ctrl must be an IMMEDIATE -> template parameter.
template <int CTRL>
__device__ __forceinline__ float dpp_add(float v) {
  int x = __builtin_amdgcn_mov_dpp(__builtin_bit_cast(int, v), CTRL, 0xF, 0xF, true);
  return v + __builtin_bit_cast(float, x);
}
#define REDUCE8(v) do { v = dpp_add<0xB1>(v); v = dpp_add<0x4E>(v); v = dpp_add<0x141>(v); } while (0)

// --- prep: combined biases, transposed Wih0, f16-packed recurrent weights ---
__global__ void prep_kernel(const float* __restrict__ Wih0,
                            const float* __restrict__ Whh0, const float* __restrict__ Wih1,
                            const float* __restrict__ Whh1,
                            const float* __restrict__ bih0, const float* __restrict__ bhh0,
                            const float* __restrict__ bih1, const float* __restrict__ bhh1,
                            float* __restrict__ Wih0T, float* __restrict__ b0c,
                            float* __restrict__ b1c,
                            u32* __restrict__ Whh0h, u32* __restrict__ Wih1h,
                            u32* __restrict__ Whh1h) {
  int g = threadIdx.x;   // 0..255 = gate row
  b0c[g] = bih0[g] + bhh0[g];
  b1c[g] = bih1[g] + bhh1[g];
  for (int d = 0; d < EMB_D; ++d) Wih0T[d * G4 + g] = Wih0[g * EMB_D + d];
  for (int d = 0; d < HID / 2; ++d) {
    Whh0h[g * 32 + d] = packh2(Whh0[g * HID + 2 * d], Whh0[g * HID + 2 * d + 1]);
    Wih1h[g * 32 + d] = packh2(Wih1[g * HID + 2 * d], Wih1[g * HID + 2 * d + 1]);
    Whh1h[g * 32 + d] = packh2(Whh1[g * HID + 2 * d], Whh1[g * HID + 2 * d + 1]);
  }
}

// --- xw0[token][gate] = emb[x[token]] . Wih0[gate] + b0, stored f16 ---
__global__ __attribute__((amdgpu_waves_per_eu(1, 4))) __launch_bounds__(256)
void xw0_kernel(
    const int* __restrict__ x, const float* __restrict__ emb,
    const float* __restrict__ Wih0T, const float* __restrict__ b0c,
    _Float16* __restrict__ xw0h) {
  __shared__ int sidx[TOK];
  __shared__ float erow[TOK][EMB_D];
  int g = threadIdx.x;
  long t0 = (long)blockIdx.x * TOK;

  if (g < TOK) sidx[g] = x[t0 + g];
  __syncthreads();
  for (int i = g; i < TOK * EMB_D; i += 256) {
    int tok = i / EMB_D;
    int d = i - tok * EMB_D;
    erow[tok][d] = emb[(long)sidx[tok] * EMB_D + d];
  }

  float w[EMB_D];
  #pragma unroll
  for (int d = 0; d < EMB_D; ++d) w[d] = Wih0T[d * G4 + g];
  float bb = b0c[g];
  __syncthreads();

  for (int tok = 0; tok < TOK; ++tok) {
    const float* ev = erow[tok];
    float a0 = bb, a1 = 0.f, a2 = 0.f, a3 = 0.f;
    #pragma unroll
    for (int d = 0; d < EMB_D; d += 4) {
      a0 = fmaf(w[d],     ev[d],     a0);
      a1 = fmaf(w[d + 1], ev[d + 1], a1);
      a2 = fmaf(w[d + 2], ev[d + 2], a2);
      a3 = fmaf(w[d + 3], ev[d + 3], a3);
    }
    xw0h[(t0 + tok) * G4 + g] = (_Float16)((a0 + a1) + (a2 + a3));
  }
}

// --- fused 2-layer recurrence, split-dot GEMV (LDS-traffic-minimal) ---
// 128 blocks (1 row), 512 threads = 8 waves. Lane = (g8 = l>>3, c = l&7).
// Waves 0-3: L0 rows 64w + 8i + g8 (Whh0 @ h0); waves 4-7: L1 rows (Wih1 @ h0
// + Whh1 @ h1). Per wave per step: ONE ds_read_b128 per h vector (lane c owns
// chunk c, broadcast across g8 groups), 8 iterations of {4|8 dot2 + 3 DPP-add
// reduce}, lane with c==i keeps row i's sum -> ONE ds_write_b32 of 64 rows.
// Phase B (waves 0-1): 4 ds_read_b32 gates + activation + ds_write_b16 h.
__global__ __attribute__((amdgpu_waves_per_eu(1, 2))) __launch_bounds__(512)
void lstm_fused_kernel(
    const _Float16* __restrict__ xw0h,
    const u32* __restrict__ Whh0h, const u32* __restrict__ Wih1h,
    const u32* __restrict__ Whh1h, const float* __restrict__ b1c,
    const float* __restrict__ W1, const float* __restrict__ clsb1,
    const float* __restrict__ W2, const float* __restrict__ clsb2,
    float* __restrict__ out) {
  const int tid = threadIdx.x;
  const int l = tid & 63;
  const int w = tid >> 6;
  const bool isL1 = (w >= 4);
  const int g8 = l >> 3;
  const int c = l & 7;
  const int rbase = 64 * (isL1 ? (w - 4) : w);
  const int b = blockIdx.x;

  __shared__ alignas(16) _Float16 h0s[HID];
  __shared__ alignas(16) _Float16 h1s[HID];
  __shared__ float gates0[G4];
  __shared__ float gates1[G4];
  __shared__ alignas(16) float hf[HID];

  // per-lane weights: iteration i -> row rbase+8i+g8, chunk c (4 u32 = 8 f16)
  uint4 wA[8], wB[8];
  {
    const u32* baseA = isL1 ? Wih1h : Whh0h;
    #pragma unroll
    for (int i = 0; i < 8; ++i) {
      int row = rbase + 8 * i + g8;
      wA[i] = *(const uint4*)(baseA + row * 32 + 4 * c);
      if (isL1) wB[i] = *(const uint4*)(Whh1h + row * 32 + 4 * c);
      else      wB[i] = uint4{0u, 0u, 0u, 0u};
    }
  }

  // phase-B state (waves 0-1): element e = l, layer = w
  const int e = l;
  float c_reg = 0.f;
  float bq0 = 0.f, bq1 = 0.f, bq2 = 0.f, bq3 = 0.f;   // L1 biases
  if (w == 1) {
    bq0 = b1c[e]; bq1 = b1c[e + 64]; bq2 = b1c[e + 128]; bq3 = b1c[e + 192];
  }
  // xw prefetch regs (wave 0): distance-2
  const _Float16* xbase = xw0h + (size_t)b * SEQ * G4;
  _Float16 xc0 = 0, xc1 = 0, xc2 = 0, xc3 = 0;
  _Float16 xn0 = 0, xn1 = 0, xn2 = 0, xn3 = 0;
  if (w == 0) {
    xc0 = xbase[e]; xc1 = xbase[e + 64]; xc2 = xbase[e + 128]; xc3 = xbase[e + 192];
    xn0 = xbase[G4 + e]; xn1 = xbase[G4 + e + 64];
    xn2 = xbase[G4 + e + 128]; xn3 = xbase[G4 + e + 192];
  }

  if (tid < HID) { h0s[tid] = (_Float16)0.f; h1s[tid] = (_Float16)0.f; }
  __syncthreads();

  for (int t = 0; t <= SEQ; ++t) {
    // ---- phase A: GEMV (all 8 waves) ----
    {
      uint4 h0c = *(const uint4*)(h0s + 8 * c);   // lane's 16B chunk of h0
      float vout = 0.f;
      if (!isL1) {
        #pragma unroll
        for (int i = 0; i < 8; ++i) {
          float a = dot2(h0c.x, wA[i].x, 0.f);
          float bsum = dot2(h0c.y, wA[i].y, 0.f);
          a = dot2(h0c.z, wA[i].z, a);
          bsum = dot2(h0c.w, wA[i].w, bsum);
          float v = a + bsum;
          REDUCE8(v);
          vout = (c == i) ? v : vout;
        }
        gates0[rbase + 8 * c + g8] = vout;
      } else {
        uint4 h1c = *(const uint4*)(h1s + 8 * c);
        #pragma unroll
        for (int i = 0; i < 8; ++i) {
          float a = dot2(h0c.x, wA[i].x, 0.f);
          float bsum = dot2(h0c.y, wA[i].y, 0.f);
          a = dot2(h0c.z, wA[i].z, a);
          bsum = dot2(h0c.w, wA[i].w, bsum);
          a = dot2(h1c.x, wB[i].x, a);
          bsum = dot2(h1c.y, wB[i].y, bsum);
          a = dot2(h1c.z, wB[i].z, a);
          bsum = dot2(h1c.w, wB[i].w, bsum);
          float v = a + bsum;
          REDUCE8(v);
          vout = (c == i) ? v : vout;
        }
        gates1[rbase + 8 * c + g8] = vout;
      }
    }
    asm volatile("s_waitcnt lgkmcnt(0)" ::: "memory");
    __builtin_amdgcn_s_barrier();

    // ---- phase B: activation (waves 0-1) ----
    if (w < 2) {
      const bool doact = (w == 0) || (t > 0);
      if (doact) {
        const float* gp = w ? gates1 : gates0;
        float gi = gp[e], gf = gp[e + 64], gg = gp[e + 128], go = gp[e + 192];
        if (w == 0) {
          gi += (float)xc0; gf += (float)xc1; gg += (float)xc2; go += (float)xc3;
        } else {
          gi += bq0; gf += bq1; gg += bq2; go += bq3;
        }
        c_reg = sigf(gf) * c_reg + sigf(gi) * tanh_fast(gg);
        float hv = sigf(go) * tanh_fast(c_reg);
        if (w == 0) {
          h0s[e] = (_Float16)hv;
        } else {
          h1s[e] = (_Float16)hv;
          if (t == SEQ) hf[e] = hv;
        }
      }
      if (w == 0) {
        xc0 = xn0; xc1 = xn1; xc2 = xn2; xc3 = xn3;
        int tn = (t + 2 < SEQ) ? (t + 2) : (SEQ - 1);
        const _Float16* xp = xbase + (size_t)tn * G4;
        xn0 = xp[e]; xn1 = xp[e + 64]; xn2 = xp[e + 128]; xn3 = xp[e + 192];
      }
    }
    asm volatile("s_waitcnt lgkmcnt(0)" ::: "memory");
    __builtin_amdgcn_s_barrier();
  }

  // ---- classifier (wave 0): z = relu(h1.W1^T + b1); out = sigmoid(z.W2 + b2)
  if (w == 0) {
    int j = l;
    const float4* wp = (const float4*)(W1 + j * HID);
    const float4* hp = (const float4*)hf;
    float z0 = clsb1[j], z1 = 0.f, z2 = 0.f, z3 = 0.f;
    #pragma unroll
    for (int cc = 0; cc < 16; ++cc) {
      float4 wv = wp[cc];
      float4 hv = hp[cc];
      z0 = fmaf(hv.x, wv.x, z0);
      z1 = fmaf(hv.y, wv.y, z1);
      z2 = fmaf(hv.z, wv.z, z2);
      z3 = fmaf(hv.w, wv.w, z3);
    }
    float z = fmaxf((z0 + z1) + (z2 + z3), 0.f);
    float v = z * W2[j];
    v += __shfl_xor(v, 1);
    v += __shfl_xor(v, 2);
    v += __shfl_xor(v, 4);
    v += __shfl_xor(v, 8);
    v += __shfl_xor(v, 16);
    v += __shfl_xor(v, 32);
    if (l == 0) out[b] = sigf(v + clsb2[0]);
  }
}

extern "C" void kernel_launch(void* const* d_in, const int* in_sizes, int n_in,
                              void* d_out, int out_size, void* d_ws, size_t ws_size,
                              hipStream_t stream) {
  const int*   x    = (const int*)d_in[0];
  const float* emb  = (const float*)d_in[1];
  const float* Wih0 = (const float*)d_in[2];
  const float* Whh0 = (const float*)d_in[3];
  const float* bih0 = (const float*)d_in[4];
  const float* bhh0 = (const float*)d_in[5];
  const float* Wih1 = (const float*)d_in[6];
  const float* Whh1 = (const float*)d_in[7];
  const float* bih1 = (const float*)d_in[8];
  const float* bhh1 = (const float*)d_in[9];
  const float* W1   = (const float*)d_in[10];
  const float* b1   = (const float*)d_in[11];
  const float* W2   = (const float*)d_in[12];
  const float* b2   = (const float*)d_in[13];
  float* out = (float*)d_out;

  char* ws = (char*)d_ws;
  const size_t XW0_BYTES = (size_t)BATCH * SEQ * G4 * sizeof(_Float16);  // 67108864
  _Float16* xw0h = (_Float16*)ws;     ws += XW0_BYTES;
  float* Wih0T   = (float*)ws;        ws += (size_t)EMB_D * G4 * sizeof(float);
  float* b0c     = (float*)ws;        ws += G4 * sizeof(float);
  float* b1c     = (float*)ws;        ws += G4 * sizeof(float);
  u32* Whh0h     = (u32*)ws;          ws += (size_t)G4 * 32 * sizeof(u32);
  u32* Wih1h     = (u32*)ws;          ws += (size_t)G4 * 32 * sizeof(u32);
  u32* Whh1h     = (u32*)ws;          ws += (size_t)G4 * 32 * sizeof(u32);

  prep_kernel<<<1, 256, 0, stream>>>(Wih0, Whh0, Wih1, Whh1, bih0, bhh0, bih1, bhh1,
                                     Wih0T, b0c, b1c, Whh0h, Wih1h, Whh1h);
  xw0_kernel<<<(BATCH * SEQ) / TOK, 256, 0, stream>>>(x, emb, Wih0T, b0c, xw0h);
  lstm_fused_kernel<<<BATCH, 512, 0, stream>>>(xw0h, Whh0h, Wih1h, Whh1h, b1c,
                                               W1, b1, W2, b2, out);
}

// Round 11
// 1003.402 us; speedup vs baseline: 1.3000x; 1.3000x over previous
//
#include <hip/hip_runtime.h>
#include <hip/hip_bf16.h>

#define EMB_D 100
#define HID 64
#define G4 256
#define BATCH 128
#define SEQ 1024
#define TOK 64

typedef _Float16 half2v __attribute__((ext_vector_type(2)));
typedef unsigned short u16;
typedef unsigned int   u32;

__device__ __forceinline__ float sigf(float x) { return 1.0f / (1.0f + __expf(-x)); }
__device__ __forceinline__ float tanh_fast(float x) {
  float t = __expf(-2.0f * fabsf(x));
  float r = (1.0f - t) / (1.0f + t);
  return copysignf(r, x);
}
__device__ __forceinline__ float dot2(u32 h, u32 w, float acc) {
  return __builtin_amdgcn_fdot2(__builtin_bit_cast(half2v, h),
                                __builtin_bit_cast(half2v, w), acc, false);
}
__device__ __forceinline__ u32 packh2(float lo, float hi) {
  u16 a = __builtin_bit_cast(u16, (_Float16)lo);
  u16 b = __builtin_bit_cast(u16, (_Float16)hi);
  return (u32)a | ((u32)b << 16);
}
// DPP quad_perm xor1 (lane <-> lane^1), single VALU instr (proven in R8)
#define QPERM_X1(x)                                                           \
  __builtin_bit_cast(float, __builtin_amdgcn_mov_dpp(                         \
      __builtin_bit_cast(int, (x)), 0xB1, 0xF, 0xF, true))

// --- prep: biases, f16-pair-packed Wih0 (transposed), packed recurrent W ---
__global__ void prep_kernel(const float* __restrict__ Wih0,
                            const float* __restrict__ Whh0, const float* __restrict__ Wih1,
                            const float* __restrict__ Whh1,
                            const float* __restrict__ bih0, const float* __restrict__ bhh0,
                            const float* __restrict__ bih1, const float* __restrict__ bhh1,
                            u32* __restrict__ Wih0T2, float* __restrict__ b0c,
                            float* __restrict__ b1c,
                            u32* __restrict__ Whh0h, u32* __restrict__ Wih1h,
                            u32* __restrict__ Whh1h) {
  int g = threadIdx.x;   // 0..255 = gate row
  b0c[g] = bih0[g] + bhh0[g];
  b1c[g] = bih1[g] + bhh1[g];
  for (int dp = 0; dp < 50; ++dp)
    Wih0T2[dp * G4 + g] = packh2(Wih0[g * EMB_D + 2 * dp], Wih0[g * EMB_D + 2 * dp + 1]);
  for (int d = 0; d < 32; ++d) {
    Whh0h[g * 32 + d] = packh2(Whh0[g * HID + 2 * d], Whh0[g * HID + 2 * d + 1]);
    Wih1h[g * 32 + d] = packh2(Wih1[g * HID + 2 * d], Wih1[g * HID + 2 * d + 1]);
    Whh1h[g * 32 + d] = packh2(Whh1[g * HID + 2 * d], Whh1[g * HID + 2 * d + 1]);
  }
}

// --- xw0: f16 dot2 GEMV, 64 tokens/block, [t][gate] f16 output ---
__global__ __attribute__((amdgpu_waves_per_eu(1, 4))) __launch_bounds__(256)
void xw0_kernel(
    const int* __restrict__ x, const float* __restrict__ emb,
    const u32* __restrict__ Wih0T2, const float* __restrict__ b0c,
    _Float16* __restrict__ xw0h) {
  __shared__ int sidx[TOK];
  __shared__ alignas(16) u32 erow[TOK][52];   // 50 f16-pairs + 2 zero pads
  int g = threadIdx.x;
  long t0 = (long)blockIdx.x * TOK;

  if (g < TOK) sidx[g] = x[t0 + g];
  __syncthreads();
  for (int i = g; i < TOK * 50; i += 256) {
    int tok = i / 50, dp = i - tok * 50;
    const float* er = emb + (size_t)sidx[tok] * EMB_D + 2 * dp;
    erow[tok][dp] = packh2(er[0], er[1]);
  }
  for (int i = g; i < TOK * 2; i += 256) erow[i >> 1][50 + (i & 1)] = 0;

  u32 wreg[52];
  #pragma unroll
  for (int dp = 0; dp < 50; ++dp) wreg[dp] = Wih0T2[dp * G4 + g];
  wreg[50] = 0; wreg[51] = 0;
  float bb = b0c[g];
  __syncthreads();

  for (int tok = 0; tok < TOK; ++tok) {
    const uint4* ep = (const uint4*)erow[tok];
    float a0 = bb, a1 = 0.f, a2 = 0.f, a3 = 0.f;
    #pragma unroll
    for (int c = 0; c < 13; ++c) {
      uint4 hv = ep[c];
      a0 = dot2(hv.x, wreg[4 * c],     a0);
      a1 = dot2(hv.y, wreg[4 * c + 1], a1);
      a2 = dot2(hv.z, wreg[4 * c + 2], a2);
      a3 = dot2(hv.w, wreg[4 * c + 3], a3);
    }
    xw0h[(t0 + tok) * G4 + g] = (_Float16)((a0 + a1) + (a2 + a3));
  }
}

// --- fused recurrence: 3-wave ownership, ONE barrier/step ---
// 128 blocks x 192 threads (3 waves). Lane l owns element l (rows l,l+64,
// l+128,l+192 = i,f,g,o quartet -> lane-local activation).
//   wave 0 (A): h0_t = act(Whh0 @ h0_{t-1} + xw_t)          [owns h0, c0]
//   wave 1 (B): p    = Wih1 @ h0_{t-1}  -> ps[] partials
//   wave 2 (C): h1_{t-2} = act(ps(lag1) + Whh1 @ h1_{t-3})  [owns h1, c1;
//               h1 buffer is C-private -> no barrier for its reuse]
// Cross-wave deps (A->B via h0, B->C via ps) consumed with 1-iter lag =>
// single s_barrier per step; h1 trails h0 by 2 iters (epilogue at t=SEQ,SEQ+1).
__global__ __attribute__((amdgpu_waves_per_eu(1, 1))) __launch_bounds__(192)
void lstm_fused_kernel(
    const _Float16* __restrict__ xw0h,
    const u32* __restrict__ Whh0h, const u32* __restrict__ Wih1h,
    const u32* __restrict__ Whh1h, const float* __restrict__ b1c,
    const float* __restrict__ W1, const float* __restrict__ clsb1,
    const float* __restrict__ W2, const float* __restrict__ clsb2,
    float* __restrict__ out) {
  const int tid = threadIdx.x;
  const int l = tid & 63;
  const int w = tid >> 6;           // 0=A, 1=B, 2=C
  const int b = blockIdx.x;

  __shared__ alignas(16) _Float16 h0s[2][HID];   // A writes, A+B read
  __shared__ alignas(16) _Float16 h1s[HID];      // C-private
  __shared__ float ps[2][4][HID];                // B writes, C reads (lag 1)
  __shared__ alignas(16) float hf[HID];

  // 4 weight rows per lane (quartet), f16-packed: 32 uint4 = 128 VGPR
  const u32* wbase = (w == 0) ? Whh0h : (w == 1) ? Wih1h : Whh1h;
  uint4 wv[4][8];
  #pragma unroll
  for (int g = 0; g < 4; ++g) {
    const uint4* p = (const uint4*)(wbase + (l + 64 * g) * 32);
    #pragma unroll
    for (int c = 0; c < 8; ++c) wv[g][c] = p[c];
  }
  #pragma unroll
  for (int g = 0; g < 4; ++g)
    #pragma unroll
    for (int c = 0; c < 8; ++c)
      asm volatile("" : "+v"(wv[g][c].x), "+v"(wv[g][c].y),
                        "+v"(wv[g][c].z), "+v"(wv[g][c].w));

  float bias0 = 0.f, bias1 = 0.f, bias2 = 0.f, bias3 = 0.f;
  if (w == 2) {
    bias0 = b1c[l]; bias1 = b1c[l + 64]; bias2 = b1c[l + 128]; bias3 = b1c[l + 192];
  }

  float c_reg = 0.f;                 // A: c0[l]; C: c1[l]
  const _Float16* xbase = xw0h + (size_t)b * SEQ * G4;
  float xc0 = 0.f, xc1 = 0.f, xc2 = 0.f, xc3 = 0.f;
  float xn0 = 0.f, xn1 = 0.f, xn2 = 0.f, xn3 = 0.f;
  if (w == 0) {
    xc0 = (float)xbase[l];        xc1 = (float)xbase[l + 64];
    xc2 = (float)xbase[l + 128];  xc3 = (float)xbase[l + 192];
    xn0 = (float)xbase[G4 + l];       xn1 = (float)xbase[G4 + l + 64];
    xn2 = (float)xbase[G4 + l + 128]; xn3 = (float)xbase[G4 + l + 192];
  }

  if (tid < 2 * HID) ((u16*)h0s)[tid] = 0;
  if (tid < HID) h1s[tid] = (_Float16)0.f;
  __syncthreads();

  for (int t = 0; t <= SEQ + 1; ++t) {
    const int rb = (t + 1) & 1, wb = t & 1;
    if (w == 0) {
      if (t < SEQ) {
        uint4 hc[8];
        const uint4* hp = (const uint4*)h0s[rb];
        #pragma unroll
        for (int c = 0; c < 8; ++c) hc[c] = hp[c];
        float gv[4];
        #pragma unroll
        for (int g = 0; g < 4; ++g) {
          float a0 = 0.f, a1 = 0.f, a2 = 0.f, a3 = 0.f;
          #pragma unroll
          for (int c = 0; c < 8; ++c) {
            a0 = dot2(hc[c].x, wv[g][c].x, a0);
            a1 = dot2(hc[c].y, wv[g][c].y, a1);
            a2 = dot2(hc[c].z, wv[g][c].z, a2);
            a3 = dot2(hc[c].w, wv[g][c].w, a3);
          }
          gv[g] = (a0 + a1) + (a2 + a3);
        }
        float gi = gv[0] + xc0, gf = gv[1] + xc1, gg = gv[2] + xc2, go = gv[3] + xc3;
        c_reg = sigf(gf) * c_reg + sigf(gi) * tanh_fast(gg);
        float hv = sigf(go) * tanh_fast(c_reg);
        float nb = QPERM_X1(hv);
        if (!(l & 1)) ((u32*)h0s[wb])[l >> 1] = packh2(hv, nb);
        xc0 = xn0; xc1 = xn1; xc2 = xn2; xc3 = xn3;
        int tn = (t + 2 < SEQ) ? (t + 2) : (SEQ - 1);
        const _Float16* xp = xbase + (size_t)tn * G4;
        xn0 = (float)xp[l];        xn1 = (float)xp[l + 64];
        xn2 = (float)xp[l + 128];  xn3 = (float)xp[l + 192];
      }
    } else if (w == 1) {
      if (t >= 1 && t <= SEQ) {
        uint4 hc[8];
        const uint4* hp = (const uint4*)h0s[rb];
        #pragma unroll
        for (int c = 0; c < 8; ++c) hc[c] = hp[c];
        #pragma unroll
        for (int g = 0; g < 4; ++g) {
          float a0 = 0.f, a1 = 0.f, a2 = 0.f, a3 = 0.f;
          #pragma unroll
          for (int c = 0; c < 8; ++c) {
            a0 = dot2(hc[c].x, wv[g][c].x, a0);
            a1 = dot2(hc[c].y, wv[g][c].y, a1);
            a2 = dot2(hc[c].z, wv[g][c].z, a2);
            a3 = dot2(hc[c].w, wv[g][c].w, a3);
          }
          ps[wb][g][l] = (a0 + a1) + (a2 + a3);
        }
      }
    } else {
      if (t >= 2) {
        uint4 hc[8];
        const uint4* hp = (const uint4*)h1s;   // h1_{t-3}, C-private
        #pragma unroll
        for (int c = 0; c < 8; ++c) hc[c] = hp[c];
        float rv[4];
        #pragma unroll
        for (int g = 0; g < 4; ++g) {
          float a0 = 0.f, a1 = 0.f, a2 = 0.f, a3 = 0.f;
          #pragma unroll
          for (int c = 0; c < 8; ++c) {
            a0 = dot2(hc[c].x, wv[g][c].x, a0);
            a1 = dot2(hc[c].y, wv[g][c].y, a1);
            a2 = dot2(hc[c].z, wv[g][c].z, a2);
            a3 = dot2(hc[c].w, wv[g][c].w, a3);
          }
          rv[g] = (a0 + a1) + (a2 + a3);
        }
        float gi = rv[0] + ps[rb][0][l] + bias0;
        float gf = rv[1] + ps[rb][1][l] + bias1;
        float gg = rv[2] + ps[rb][2][l] + bias2;
        float go = rv[3] + ps[rb][3][l] + bias3;
        c_reg = sigf(gf) * c_reg + sigf(gi) * tanh_fast(gg);
        float hv = sigf(go) * tanh_fast(c_reg);
        float nb = QPERM_X1(hv);
        if (!(l & 1)) ((u32*)h1s)[l >> 1] = packh2(hv, nb);
        if (t == SEQ + 1) hf[l] = hv;
      }
    }
    asm volatile("s_waitcnt lgkmcnt(0)" ::: "memory");
    __builtin_amdgcn_s_barrier();
  }

  // classifier (wave 0): z = relu(h1.W1^T + b1); out = sigmoid(z.W2 + b2)
  if (w == 0) {
    int j = l;
    const float4* wp = (const float4*)(W1 + j * HID);
    const float4* hp = (const float4*)hf;
    float z0 = clsb1[j], z1 = 0.f, z2 = 0.f, z3 = 0.f;
    #pragma unroll
    for (int cc = 0; cc < 16; ++cc) {
      float4 wvv = wp[cc];
      float4 hv = hp[cc];
      z0 = fmaf(hv.x, wvv.x, z0);
      z1 = fmaf(hv.y, wvv.y, z1);
      z2 = fmaf(hv.z, wvv.z, z2);
      z3 = fmaf(hv.w, wvv.w, z3);
    }
    float z = fmaxf((z0 + z1) + (z2 + z3), 0.f);
    float v = z * W2[j];
    v += __shfl_xor(v, 1);
    v += __shfl_xor(v, 2);
    v += __shfl_xor(v, 4);
    v += __shfl_xor(v, 8);
    v += __shfl_xor(v, 16);
    v += __shfl_xor(v, 32);
    if (l == 0) out[b] = sigf(v + clsb2[0]);
  }
}

extern "C" void kernel_launch(void* const* d_in, const int* in_sizes, int n_in,
                              void* d_out, int out_size, void* d_ws, size_t ws_size,
                              hipStream_t stream) {
  const int*   x    = (const int*)d_in[0];
  const float* emb  = (const float*)d_in[1];
  const float* Wih0 = (const float*)d_in[2];
  const float* Whh0 = (const float*)d_in[3];
  const float* bih0 = (const float*)d_in[4];
  const float* bhh0 = (const float*)d_in[5];
  const float* Wih1 = (const float*)d_in[6];
  const float* Whh1 = (const float*)d_in[7];
  const float* bih1 = (const float*)d_in[8];
  const float* bhh1 = (const float*)d_in[9];
  const float* W1   = (const float*)d_in[10];
  const float* b1   = (const float*)d_in[11];
  const float* W2   = (const float*)d_in[12];
  const float* b2   = (const float*)d_in[13];
  float* out = (float*)d_out;

  char* ws = (char*)d_ws;
  const size_t XW0_BYTES = (size_t)BATCH * SEQ * G4 * sizeof(_Float16);  // 67108864
  _Float16* xw0h = (_Float16*)ws;     ws += XW0_BYTES;
  u32* Wih0T2    = (u32*)ws;          ws += (size_t)50 * G4 * sizeof(u32);
  float* b0c     = (float*)ws;        ws += G4 * sizeof(float);
  float* b1c     = (float*)ws;        ws += G4 * sizeof(float);
  u32* Whh0h     = (u32*)ws;          ws += (size_t)G4 * 32 * sizeof(u32);
  u32* Wih1h     = (u32*)ws;          ws += (size_t)G4 * 32 * sizeof(u32);
  u32* Whh1h     = (u32*)ws;          ws += (size_t)G4 * 32 * sizeof(u32);

  prep_kernel<<<1, 256, 0, stream>>>(Wih0, Whh0, Wih1, Whh1, bih0, bhh0, bih1, bhh1,
                                     Wih0T2, b0c, b1c, Whh0h, Wih1h, Whh1h);
  xw0_kernel<<<(BATCH * SEQ) / TOK, 256, 0, stream>>>(x, emb, Wih0T2, b0c, xw0h);
  lstm_fused_kernel<<<BATCH, 192, 0, stream>>>(xw0h, Whh0h, Wih1h, Whh1h, b1c,
                                               W1, b1, W2, b2, out);
}